// Round 1
// baseline (377.437 us; speedup 1.0000x reference)
//
#include <hip/hip_runtime.h>

typedef unsigned short ushort_t;
typedef __bf16 bf16_t;
typedef bf16_t bf16x8 __attribute__((ext_vector_type(8)));
typedef float floatx4 __attribute__((ext_vector_type(4)));
typedef ushort_t ushortx8 __attribute__((ext_vector_type(8)));

struct alignas(8) us4 { ushort_t x, y, z, w; };

__device__ __forceinline__ ushort_t f2bf(float f) {
  union { float f; unsigned int u; } v; v.f = f;
  unsigned int u = v.u;
  return (ushort_t)((u + 0x7fffu + ((u >> 16) & 1u)) >> 16);
}

__device__ __forceinline__ void async16(const void* g, void* l) {
  __builtin_amdgcn_global_load_lds(
      (const __attribute__((address_space(1))) unsigned int*)g,
      (__attribute__((address_space(3))) unsigned int*)l, 16, 0, 0);
}

// ---------------- convert / transpose ----------------

__global__ __launch_bounds__(256) void k_cvt_x(const float* __restrict__ in,
                                               ushort_t* __restrict__ out) {
  size_t i = ((size_t)blockIdx.x * 256 + threadIdx.x) * 8;
  float4 a = *(const float4*)(in + i);
  float4 b = *(const float4*)(in + i + 4);
  ushortx8 o;
  o[0] = f2bf(a.x); o[1] = f2bf(a.y); o[2] = f2bf(a.z); o[3] = f2bf(a.w);
  o[4] = f2bf(b.x); o[5] = f2bf(b.y); o[6] = f2bf(b.z); o[7] = f2bf(b.w);
  *(ushortx8*)(out + i) = o;
}

// out[c][r] = bf16(in[r][c]);  in: R x C f32, out: C x R bf16
__global__ __launch_bounds__(256) void k_transpose_bf16(const float* __restrict__ in,
                                                        ushort_t* __restrict__ out,
                                                        int R, int C) {
  __shared__ float tile[32][33];
  int c0 = blockIdx.x * 32, r0 = blockIdx.y * 32;
  int tx = threadIdx.x, ty = threadIdx.y;  // 32 x 8
#pragma unroll
  for (int i = 0; i < 32; i += 8)
    tile[ty + i][tx] = in[(size_t)(r0 + ty + i) * C + c0 + tx];
  __syncthreads();
#pragma unroll
  for (int i = 0; i < 32; i += 8)
    out[(size_t)(c0 + ty + i) * R + r0 + tx] = f2bf(tile[tx][ty + i]);
}

// ---------------- gemm_bt mainloop (128x128 tile, K=768, BK=32) ----------------
// C[m][n] = sum_k A[m][k] * Bt[n][k]; both A and Bt row-major with stride 768.

__device__ __forceinline__ void gemm_bt_mainloop(const ushort_t* __restrict__ A,
                                                 const ushort_t* __restrict__ Bt,
                                                 int m0, int n0,
                                                 ushort_t* sA, ushort_t* sB,
                                                 floatx4 acc[4][4]) {
  const int t = threadIdx.x;
  const int lane = t & 63, w = t >> 6;
  const int wr = w >> 1, wc = w & 1;
  const int lr = lane & 15, qd = lane >> 4;
  const ushort_t* gA = A + (size_t)(m0 + (t >> 2)) * 768 + (t & 3) * 8;
  const ushort_t* gB = Bt + (size_t)(n0 + (t >> 2)) * 768 + (t & 3) * 8;
  char* lA = (char*)sA + t * 16;
  char* lB = (char*)sB + t * 16;
  for (int k0 = 0; k0 < 768; k0 += 32) {
    __syncthreads();
    async16(gA + k0, lA);
    async16(gA + k0 + 64 * 768, lA + 4096);
    async16(gB + k0, lB);
    async16(gB + k0 + 64 * 768, lB + 4096);
    asm volatile("s_waitcnt vmcnt(0)" ::: "memory");
    __syncthreads();
    bf16x8 af[4], bfr[4];
#pragma unroll
    for (int i = 0; i < 4; ++i)
      af[i] = *(const bf16x8*)((const char*)sA + ((wr * 64 + i * 16 + lr) * 32 + qd * 8) * 2);
#pragma unroll
    for (int j = 0; j < 4; ++j)
      bfr[j] = *(const bf16x8*)((const char*)sB + ((wc * 64 + j * 16 + lr) * 32 + qd * 8) * 2);
#pragma unroll
    for (int i = 0; i < 4; ++i)
#pragma unroll
      for (int j = 0; j < 4; ++j)
        acc[i][j] = __builtin_amdgcn_mfma_f32_16x16x32_bf16(af[i], bfr[j], acc[i][j], 0, 0, 0);
  }
}

// ---------------- QKV GEMM + bias + zeta + scale, scatter to q/k/vt ----------------

__global__ __launch_bounds__(256) void k_qkv(const ushort_t* __restrict__ xb,
                                             const ushort_t* __restrict__ WqT,
                                             const float* __restrict__ bqkv,
                                             const float* __restrict__ zeta,
                                             ushort_t* __restrict__ qb,
                                             ushort_t* __restrict__ kb,
                                             ushort_t* __restrict__ vtb) {
  __shared__ alignas(16) ushort_t sA[128 * 32];
  __shared__ alignas(16) ushort_t sB[128 * 32];
  floatx4 acc[4][4] = {};
  const int m0 = blockIdx.y * 128, n0 = blockIdx.x * 128;
  gemm_bt_mainloop(xb, WqT, m0, n0, sA, sB, acc);
  const int t = threadIdx.x, lane = t & 63, w = t >> 6;
  const int wr = w >> 1, wc = w & 1, lr = lane & 15, qd = lane >> 4;
  const int tq = n0 / 768;  // 0=q 1=k 2=v (tile never straddles: 768 % 128 == 0)
#pragma unroll
  for (int j = 0; j < 4; ++j) {
    int n = n0 + wc * 64 + j * 16 + lr;
    int nc = n - tq * 768;
    int h = nc >> 6, dim = n & 63;
    float bias = bqkv[n];
    float zv = zeta[nc];
    float mult = (tq == 0) ? zv * 0.125f : zv;  // fold d^-0.5 into q
    if (tq < 2) {
      ushort_t* dst = (tq == 0) ? qb : kb;
#pragma unroll
      for (int i = 0; i < 4; ++i) {
        int mbase = m0 + wr * 64 + i * 16 + qd * 4;
#pragma unroll
        for (int r = 0; r < 4; ++r) {
          int m = mbase + r;
          int b = m >> 10, seq = m & 1023;
          dst[(((size_t)b * 12 + h) * 1024 + seq) * 64 + dim] = f2bf((acc[i][j][r] + bias) * mult);
        }
      }
    } else {
#pragma unroll
      for (int i = 0; i < 4; ++i) {
        int mbase = m0 + wr * 64 + i * 16 + qd * 4;
        int b = mbase >> 10, seq = mbase & 1023;
        us4 pk;
        pk.x = f2bf((acc[i][j][0] + bias) * mult);
        pk.y = f2bf((acc[i][j][1] + bias) * mult);
        pk.z = f2bf((acc[i][j][2] + bias) * mult);
        pk.w = f2bf((acc[i][j][3] + bias) * mult);
        *(us4*)&vtb[(((size_t)b * 12 + h) * 64 + dim) * 1024 + seq] = pk;
      }
    }
  }
}

// ---------------- flash attention: S^T = K*Q^T, O^T = Vt*P^T ----------------

__global__ __launch_bounds__(256) void k_attn(const ushort_t* __restrict__ qg,
                                              const ushort_t* __restrict__ kg,
                                              const ushort_t* __restrict__ vg,
                                              const unsigned char* __restrict__ mask,
                                              ushort_t* __restrict__ ob) {
  __shared__ alignas(16) ushort_t sK[128 * 64];
  __shared__ alignas(16) ushort_t sV[64 * 128];
  __shared__ alignas(16) ushort_t sP[4 * 32 * 136];
  __shared__ alignas(16) float maskadd[128];
  const int t = threadIdx.x, lane = t & 63, w = t >> 6;
  const int lr = lane & 15, qd = lane >> 4;
  const int bh = blockIdx.y, b = bh / 12, h = bh % 12;
  const int qrow0 = blockIdx.x * 128 + w * 32;
  const ushort_t* qp = qg + (size_t)bh * 65536;
  const ushort_t* kp = kg + (size_t)bh * 65536;
  const ushort_t* vp = vg + (size_t)bh * 65536;
  const unsigned char* mp = mask + b * 1024;

  // Q fragments (B-operand of K*Q^T), kept in registers for all 8 K-tiles
  bf16x8 qf[2][2];
#pragma unroll
  for (int ns = 0; ns < 2; ++ns)
#pragma unroll
    for (int kk = 0; kk < 2; ++kk)
      qf[ns][kk] = *(const bf16x8*)(qp + (size_t)(qrow0 + ns * 16 + lr) * 64 + kk * 32 + qd * 8);

  floatx4 o[4][2] = {};
  float mst[2] = {-1e30f, -1e30f};
  float lst[2] = {0.f, 0.f};
  ushort_t* sPw = sP + w * 32 * 136;

  for (int kt = 0; kt < 8; ++kt) {
    __syncthreads();
    const ushort_t* kpt = kp + kt * 128 * 64;  // contiguous 16 KB
#pragma unroll
    for (int it = 0; it < 4; ++it)
      async16(kpt + (it * 256 + t) * 8, (char*)sK + (it * 256 + t) * 16);
    const ushort_t* vpt = vp + kt * 128;  // 64 rows x 256 B, row stride 2048 B
#pragma unroll
    for (int it = 0; it < 4; ++it)
      async16(vpt + (size_t)(it * 16 + (t >> 4)) * 1024 + (t & 15) * 8,
              (char*)sV + it * 4096 + t * 16);
    if (t < 128) maskadd[t] = mp[kt * 128 + t] ? -1e30f : 0.0f;
    asm volatile("s_waitcnt vmcnt(0)" ::: "memory");
    __syncthreads();

    // S^T tile: rows = 128 keys (8 msub), cols = 32 qrows (2 nsub)
    floatx4 s[8][2] = {};
#pragma unroll
    for (int kk = 0; kk < 2; ++kk) {
#pragma unroll
      for (int ms = 0; ms < 8; ++ms) {
        bf16x8 ak = *(const bf16x8*)((const char*)sK + ((ms * 16 + lr) * 64 + kk * 32 + qd * 8) * 2);
#pragma unroll
        for (int ns = 0; ns < 2; ++ns)
          s[ms][ns] = __builtin_amdgcn_mfma_f32_16x16x32_bf16(ak, qf[ns][kk], s[ms][ns], 0, 0, 0);
      }
    }
    // key mask (additive -1e30)
#pragma unroll
    for (int ms = 0; ms < 8; ++ms) {
      float4 mk = *(const float4*)&maskadd[ms * 16 + qd * 4];
#pragma unroll
      for (int ns = 0; ns < 2; ++ns) {
        s[ms][ns][0] += mk.x; s[ms][ns][1] += mk.y;
        s[ms][ns][2] += mk.z; s[ms][ns][3] += mk.w;
      }
    }
    // online softmax over keys (rows of S^T) for each qrow (col)
    float tmax[2] = {-1e30f, -1e30f};
#pragma unroll
    for (int ms = 0; ms < 8; ++ms)
#pragma unroll
      for (int ns = 0; ns < 2; ++ns)
#pragma unroll
        for (int r = 0; r < 4; ++r) tmax[ns] = fmaxf(tmax[ns], s[ms][ns][r]);
#pragma unroll
    for (int ns = 0; ns < 2; ++ns) {
      tmax[ns] = fmaxf(tmax[ns], __shfl_xor(tmax[ns], 16));
      tmax[ns] = fmaxf(tmax[ns], __shfl_xor(tmax[ns], 32));
    }
    float alpha[2], tsum[2] = {0.f, 0.f};
#pragma unroll
    for (int ns = 0; ns < 2; ++ns) {
      float mnew = fmaxf(mst[ns], tmax[ns]);
      alpha[ns] = __expf(mst[ns] - mnew);
      mst[ns] = mnew;
    }
#pragma unroll
    for (int ms = 0; ms < 8; ++ms)
#pragma unroll
      for (int ns = 0; ns < 2; ++ns)
#pragma unroll
        for (int r = 0; r < 4; ++r) {
          float p = __expf(s[ms][ns][r] - mst[ns]);
          s[ms][ns][r] = p;
          tsum[ns] += p;
        }
#pragma unroll
    for (int ns = 0; ns < 2; ++ns) {
      tsum[ns] += __shfl_xor(tsum[ns], 16);
      tsum[ns] += __shfl_xor(tsum[ns], 32);
      lst[ns] = lst[ns] * alpha[ns] + tsum[ns];
    }
#pragma unroll
    for (int ds = 0; ds < 4; ++ds)
#pragma unroll
      for (int ns = 0; ns < 2; ++ns) {
        o[ds][ns][0] *= alpha[ns]; o[ds][ns][1] *= alpha[ns];
        o[ds][ns][2] *= alpha[ns]; o[ds][ns][3] *= alpha[ns];
      }
    // write P[qrow][key] (4 consecutive keys per lane -> packed b64 writes)
#pragma unroll
    for (int ms = 0; ms < 8; ++ms)
#pragma unroll
      for (int ns = 0; ns < 2; ++ns) {
        us4 pk;
        pk.x = f2bf(s[ms][ns][0]); pk.y = f2bf(s[ms][ns][1]);
        pk.z = f2bf(s[ms][ns][2]); pk.w = f2bf(s[ms][ns][3]);
        *(us4*)&sPw[(ns * 16 + lr) * 136 + ms * 16 + qd * 4] = pk;
      }
    asm volatile("s_waitcnt lgkmcnt(0)" ::: "memory");
    // O^T += Vt * P^T
#pragma unroll
    for (int kk = 0; kk < 4; ++kk) {
      bf16x8 pb[2];
#pragma unroll
      for (int ns = 0; ns < 2; ++ns)
        pb[ns] = *(const bf16x8*)((const char*)sPw + ((ns * 16 + lr) * 136 + kk * 32 + qd * 8) * 2);
#pragma unroll
      for (int ds = 0; ds < 4; ++ds) {
        bf16x8 av = *(const bf16x8*)((const char*)sV + ((ds * 16 + lr) * 128 + kk * 32 + qd * 8) * 2);
#pragma unroll
        for (int ns = 0; ns < 2; ++ns)
          o[ds][ns] = __builtin_amdgcn_mfma_f32_16x16x32_bf16(av, pb[ns], o[ds][ns], 0, 0, 0);
      }
    }
  }
  // epilogue: O[qrow][dim] / l -> obuf (B,N,H*d) bf16
#pragma unroll
  for (int ns = 0; ns < 2; ++ns) {
    float rl = 1.0f / lst[ns];
    size_t row = (size_t)(b * 1024 + qrow0 + ns * 16 + lr) * 768 + h * 64;
#pragma unroll
    for (int ds = 0; ds < 4; ++ds) {
      us4 ov;
      ov.x = f2bf(o[ds][ns][0] * rl); ov.y = f2bf(o[ds][ns][1] * rl);
      ov.z = f2bf(o[ds][ns][2] * rl); ov.w = f2bf(o[ds][ns][3] * rl);
      *(us4*)&ob[row + ds * 16 + qd * 4] = ov;
    }
  }
}

// ---------------- output projection ----------------

__global__ __launch_bounds__(256) void k_proj(const ushort_t* __restrict__ ob,
                                              const ushort_t* __restrict__ WpT,
                                              const float* __restrict__ bproj,
                                              float* __restrict__ out) {
  __shared__ alignas(16) ushort_t sA[128 * 32];
  __shared__ alignas(16) ushort_t sB[128 * 32];
  floatx4 acc[4][4] = {};
  const int m0 = blockIdx.y * 128, n0 = blockIdx.x * 128;
  gemm_bt_mainloop(ob, WpT, m0, n0, sA, sB, acc);
  const int t = threadIdx.x, lane = t & 63, w = t >> 6;
  const int wr = w >> 1, wc = w & 1, lr = lane & 15, qd = lane >> 4;
#pragma unroll
  for (int j = 0; j < 4; ++j) {
    int n = n0 + wc * 64 + j * 16 + lr;
    float bias = bproj[n];
#pragma unroll
    for (int i = 0; i < 4; ++i) {
      int mbase = m0 + wr * 64 + i * 16 + qd * 4;
#pragma unroll
      for (int r = 0; r < 4; ++r)
        out[(size_t)(mbase + r) * 768 + n] = acc[i][j][r] + bias;
    }
  }
}

// ---------------- launch ----------------

extern "C" void kernel_launch(void* const* d_in, const int* in_sizes, int n_in,
                              void* d_out, int out_size, void* d_ws, size_t ws_size,
                              hipStream_t stream) {
  const float* x = (const float*)d_in[0];
  const float* Wqkv = (const float*)d_in[1];
  const float* bqkv = (const float*)d_in[2];
  const float* zeta = (const float*)d_in[3];
  const float* Wproj = (const float*)d_in[4];
  const float* bproj = (const float*)d_in[5];
  const unsigned char* mask = (const unsigned char*)d_in[6];
  float* out = (float*)d_out;
  char* ws = (char*)d_ws;
  // workspace layout (bytes)
  ushort_t* xb  = (ushort_t*)(ws);              // 16384x768 bf16   (25,165,824)
  ushort_t* WqT = (ushort_t*)(ws + 25165824);   // 2304x768 bf16    ( 3,538,944)
  ushort_t* WpT = (ushort_t*)(ws + 28704768);   // 768x768 bf16     ( 1,179,648)
  ushort_t* qb  = (ushort_t*)(ws + 29884416);   // (B,H,N,d) bf16   (25,165,824)
  ushort_t* kb  = (ushort_t*)(ws + 55050240);   // (B,H,N,d) bf16   (25,165,824)
  ushort_t* vtb = (ushort_t*)(ws + 80216064);   // (B,H,d,N) bf16   (25,165,824)
  ushort_t* ob  = xb;  // xb is dead after k_qkv; reuse as attention output

  k_cvt_x<<<dim3(6144), dim3(256), 0, stream>>>(x, xb);
  k_transpose_bf16<<<dim3(72, 24), dim3(32, 8), 0, stream>>>(Wqkv, WqT, 768, 2304);
  k_transpose_bf16<<<dim3(24, 24), dim3(32, 8), 0, stream>>>(Wproj, WpT, 768, 768);
  k_qkv<<<dim3(18, 128), dim3(256), 0, stream>>>(xb, WqT, bqkv, zeta, qb, kb, vtb);
  k_attn<<<dim3(8, 192), dim3(256), 0, stream>>>(qb, kb, vtb, mask, ob);
  k_proj<<<dim3(6, 128), dim3(256), 0, stream>>>(ob, WpT, bproj, out);
}

// Round 2
// 373.578 us; speedup vs baseline: 1.0103x; 1.0103x over previous
//
#include <hip/hip_runtime.h>
#include <hip/hip_bf16.h>

typedef unsigned short ushort_t;
typedef __bf16 bf16_t;
typedef bf16_t bf16x8 __attribute__((ext_vector_type(8)));
typedef float floatx4 __attribute__((ext_vector_type(4)));
typedef ushort_t ushortx8 __attribute__((ext_vector_type(8)));

struct alignas(8) us4 { ushort_t x, y, z, w; };

__device__ __forceinline__ ushort_t f2bf(float f) {
  union { float f; unsigned int u; } v; v.f = f;
  unsigned int u = v.u;
  return (ushort_t)((u + 0x7fffu + ((u >> 16) & 1u)) >> 16);
}

__device__ __forceinline__ unsigned int pk_bf16(float a, float b) {
  __hip_bfloat162 h = __float22bfloat162_rn(float2{a, b});  // .x in low half
  union { __hip_bfloat162 h; unsigned int u; } v; v.h = h;
  return v.u;
}

__device__ __forceinline__ void async16(const void* g, void* l) {
  __builtin_amdgcn_global_load_lds(
      (const __attribute__((address_space(1))) unsigned int*)g,
      (__attribute__((address_space(3))) unsigned int*)l, 16, 0, 0);
}

#define LOG2E 1.44269504088896340736f

// ---------------- convert / transpose ----------------

__global__ __launch_bounds__(256) void k_cvt_x(const float* __restrict__ in,
                                               ushort_t* __restrict__ out) {
  size_t i = ((size_t)blockIdx.x * 256 + threadIdx.x) * 8;
  float4 a = *(const float4*)(in + i);
  float4 b = *(const float4*)(in + i + 4);
  ushortx8 o;
  o[0] = f2bf(a.x); o[1] = f2bf(a.y); o[2] = f2bf(a.z); o[3] = f2bf(a.w);
  o[4] = f2bf(b.x); o[5] = f2bf(b.y); o[6] = f2bf(b.z); o[7] = f2bf(b.w);
  *(ushortx8*)(out + i) = o;
}

__global__ __launch_bounds__(256) void k_transpose_bf16(const float* __restrict__ in,
                                                        ushort_t* __restrict__ out,
                                                        int R, int C) {
  __shared__ float tile[32][33];
  int c0 = blockIdx.x * 32, r0 = blockIdx.y * 32;
  int tx = threadIdx.x, ty = threadIdx.y;  // 32 x 8
#pragma unroll
  for (int i = 0; i < 32; i += 8)
    tile[ty + i][tx] = in[(size_t)(r0 + ty + i) * C + c0 + tx];
  __syncthreads();
#pragma unroll
  for (int i = 0; i < 32; i += 8)
    out[(size_t)(c0 + ty + i) * R + r0 + tx] = f2bf(tile[tx][ty + i]);
}

// ---------------- gemm_bt mainloop (128x128 tile, K=768, BK=32) ----------------
// XOR-swizzled LDS: chunk (r,c) of 8 elems stored at position r*4 + (c ^ ((r>>1)&3)).
// 2-way max bank aliasing on ds_read_b128 (free), staging stays lane-contiguous.

__device__ __forceinline__ void gemm_bt_mainloop(const ushort_t* __restrict__ A,
                                                 const ushort_t* __restrict__ Bt,
                                                 int m0, int n0,
                                                 ushort_t* sA, ushort_t* sB,
                                                 floatx4 acc[4][4]) {
  const int t = threadIdx.x;
  const int lane = t & 63, w = t >> 6;
  const int wr = w >> 1, wc = w & 1;
  const int lr = lane & 15, qd = lane >> 4;
  const int swz = ((t & 3) ^ ((t >> 3) & 3)) * 8;  // swizzled col chunk for staging
  const ushort_t* gA = A + (size_t)(m0 + (t >> 2)) * 768 + swz;
  const ushort_t* gB = Bt + (size_t)(n0 + (t >> 2)) * 768 + swz;
  char* lA = (char*)sA + t * 16;
  char* lB = (char*)sB + t * 16;
  const int rsz = (qd ^ ((lr >> 1) & 3)) * 16;  // swizzled chunk byte-offset for reads
  for (int k0 = 0; k0 < 768; k0 += 32) {
    __syncthreads();
    async16(gA + k0, lA);
    async16(gA + k0 + 64 * 768, lA + 4096);
    async16(gB + k0, lB);
    async16(gB + k0 + 64 * 768, lB + 4096);
    asm volatile("s_waitcnt vmcnt(0)" ::: "memory");
    __syncthreads();
    bf16x8 af[4], bfr[4];
#pragma unroll
    for (int i = 0; i < 4; ++i)
      af[i] = *(const bf16x8*)((const char*)sA + (wr * 64 + i * 16 + lr) * 64 + rsz);
#pragma unroll
    for (int j = 0; j < 4; ++j)
      bfr[j] = *(const bf16x8*)((const char*)sB + (wc * 64 + j * 16 + lr) * 64 + rsz);
#pragma unroll
    for (int i = 0; i < 4; ++i)
#pragma unroll
      for (int j = 0; j < 4; ++j)
        acc[i][j] = __builtin_amdgcn_mfma_f32_16x16x32_bf16(af[i], bfr[j], acc[i][j], 0, 0, 0);
  }
}

// ---------------- QKV GEMM + bias + zeta + scale, scatter to q/k/vt ----------------

__global__ __launch_bounds__(256) void k_qkv(const ushort_t* __restrict__ xb,
                                             const ushort_t* __restrict__ WqT,
                                             const float* __restrict__ bqkv,
                                             const float* __restrict__ zeta,
                                             ushort_t* __restrict__ qb,
                                             ushort_t* __restrict__ kb,
                                             ushort_t* __restrict__ vtb) {
  __shared__ alignas(16) ushort_t sA[128 * 32];
  __shared__ alignas(16) ushort_t sB[128 * 32];
  floatx4 acc[4][4] = {};
  const int m0 = blockIdx.y * 128, n0 = blockIdx.x * 128;
  gemm_bt_mainloop(xb, WqT, m0, n0, sA, sB, acc);
  const int t = threadIdx.x, lane = t & 63, w = t >> 6;
  const int wr = w >> 1, wc = w & 1, lr = lane & 15, qd = lane >> 4;
  const int tq = n0 / 768;  // 0=q 1=k 2=v (tile never straddles: 768 % 128 == 0)
#pragma unroll
  for (int j = 0; j < 4; ++j) {
    int n = n0 + wc * 64 + j * 16 + lr;
    int nc = n - tq * 768;
    int h = nc >> 6, dim = n & 63;
    float bias = bqkv[n];
    float zv = zeta[nc];
    // fold d^-0.5 AND log2(e) into q so attention softmax can use exp2
    float mult = (tq == 0) ? zv * 0.125f * LOG2E : zv;
    if (tq < 2) {
      ushort_t* dst = (tq == 0) ? qb : kb;
#pragma unroll
      for (int i = 0; i < 4; ++i) {
        int mbase = m0 + wr * 64 + i * 16 + qd * 4;
#pragma unroll
        for (int r = 0; r < 4; ++r) {
          int m = mbase + r;
          int b = m >> 10, seq = m & 1023;
          dst[(((size_t)b * 12 + h) * 1024 + seq) * 64 + dim] = f2bf((acc[i][j][r] + bias) * mult);
        }
      }
    } else {
#pragma unroll
      for (int i = 0; i < 4; ++i) {
        int mbase = m0 + wr * 64 + i * 16 + qd * 4;
        int b = mbase >> 10, seq = mbase & 1023;
        us4 pk;
        pk.x = f2bf((acc[i][j][0] + bias) * mult);
        pk.y = f2bf((acc[i][j][1] + bias) * mult);
        pk.z = f2bf((acc[i][j][2] + bias) * mult);
        pk.w = f2bf((acc[i][j][3] + bias) * mult);
        *(us4*)&vtb[(((size_t)b * 12 + h) * 64 + dim) * 1024 + seq] = pk;
      }
    }
  }
}

// ---------------- flash attention: S^T = K*Q^T, O^T = Vt*P^T ----------------
// LDS: union region [0,32768): sK (16 KB, swizzled) overlaid by per-wave sP
// (4 x 8 KB, swizzled); sV at 32768 (16 KB, swizzled); mask floats at 49152.
// Total 49664 B -> 3 blocks/CU.

__global__ __launch_bounds__(256, 3) void k_attn(const ushort_t* __restrict__ qg,
                                                 const ushort_t* __restrict__ kg,
                                                 const ushort_t* __restrict__ vg,
                                                 const unsigned char* __restrict__ mask,
                                                 ushort_t* __restrict__ ob) {
  __shared__ alignas(16) char smem[49664];
  char* sV = smem + 32768;
  float* maskadd = (float*)(smem + 49152);
  const int t = threadIdx.x, lane = t & 63, w = t >> 6;
  const int lr = lane & 15, qd = lane >> 4;
  // XCD swizzle: all 8 q-tiles of one bh adjacent on the same XCD (lin%8)
  const int lin = blockIdx.x;
  const int bh = (lin & 7) + 8 * (lin >> 6);
  const int qt = (lin >> 3) & 7;
  const int b = bh / 12, h = bh % 12;
  const int qrow0 = qt * 128 + w * 32;
  const ushort_t* qp = qg + (size_t)bh * 65536;
  const ushort_t* kp = kg + (size_t)bh * 65536;
  const ushort_t* vp = vg + (size_t)bh * 65536;
  const unsigned char* mp = mask + b * 1024;

  // Q fragments (B-operand of K*Q^T), kept in registers for all 8 K-tiles
  bf16x8 qf[2][2];
#pragma unroll
  for (int ns = 0; ns < 2; ++ns)
#pragma unroll
    for (int kk = 0; kk < 2; ++kk)
      qf[ns][kk] = *(const bf16x8*)(qp + (size_t)(qrow0 + ns * 16 + lr) * 64 + kk * 32 + qd * 8);

  floatx4 o[4][2] = {};
  float mst[2] = {-1e30f, -1e30f};
  float lst[2] = {0.f, 0.f};
  char* sPw = smem + w * 8192;

  for (int kt = 0; kt < 8; ++kt) {
    __syncthreads();  // prev PV reads (sP union + sV) complete
    // stage K: 128 rows x 8 chunks, chunk (r,c) at pos r*8 + (c ^ (r&7))
    const ushort_t* kpt = kp + kt * 8192;
#pragma unroll
    for (int it = 0; it < 4; ++it) {
      int p = it * 256 + t;
      int r = p >> 3, cs = (p & 7) ^ (r & 7);
      async16(kpt + r * 64 + cs * 8, smem + p * 16);
    }
    // stage V: 64 rows (d) x 16 chunks (keys), chunk (r,c) at pos r*16 + (c ^ (r&15))
    const ushort_t* vpt = vp + kt * 128;
#pragma unroll
    for (int it = 0; it < 4; ++it) {
      int p = it * 256 + t;
      int r = p >> 4, cs = (p & 15) ^ (r & 15);
      async16(vpt + (size_t)r * 1024 + cs * 8, sV + p * 16);
    }
    if (t < 128) maskadd[t] = mp[kt * 128 + t] ? -1e30f : 0.0f;
    asm volatile("s_waitcnt vmcnt(0)" ::: "memory");
    __syncthreads();

    // S^T tile: rows = 128 keys (8 msub), cols = 32 qrows (2 nsub)
    floatx4 s[8][2] = {};
#pragma unroll
    for (int kk = 0; kk < 2; ++kk) {
#pragma unroll
      for (int ms = 0; ms < 8; ++ms) {
        bf16x8 ak = *(const bf16x8*)(smem + (ms * 16 + lr) * 128 +
                                     ((kk * 4 + qd) ^ (lr & 7)) * 16);
#pragma unroll
        for (int ns = 0; ns < 2; ++ns)
          s[ms][ns] = __builtin_amdgcn_mfma_f32_16x16x32_bf16(ak, qf[ns][kk], s[ms][ns], 0, 0, 0);
      }
    }
    // key mask (additive -1e30)
#pragma unroll
    for (int ms = 0; ms < 8; ++ms) {
      float4 mk = *(const float4*)&maskadd[ms * 16 + qd * 4];
#pragma unroll
      for (int ns = 0; ns < 2; ++ns) {
        s[ms][ns][0] += mk.x; s[ms][ns][1] += mk.y;
        s[ms][ns][2] += mk.z; s[ms][ns][3] += mk.w;
      }
    }
    // online softmax in log2 domain (q was pre-scaled by log2e)
    float tmax[2] = {-1e30f, -1e30f};
#pragma unroll
    for (int ms = 0; ms < 8; ++ms)
#pragma unroll
      for (int ns = 0; ns < 2; ++ns)
#pragma unroll
        for (int r = 0; r < 4; ++r) tmax[ns] = fmaxf(tmax[ns], s[ms][ns][r]);
#pragma unroll
    for (int ns = 0; ns < 2; ++ns) {
      tmax[ns] = fmaxf(tmax[ns], __shfl_xor(tmax[ns], 16));
      tmax[ns] = fmaxf(tmax[ns], __shfl_xor(tmax[ns], 32));
    }
    float alpha[2], tsum[2] = {0.f, 0.f};
#pragma unroll
    for (int ns = 0; ns < 2; ++ns) {
      float mnew = fmaxf(mst[ns], tmax[ns]);
      alpha[ns] = __builtin_amdgcn_exp2f(mst[ns] - mnew);
      mst[ns] = mnew;
    }
#pragma unroll
    for (int ms = 0; ms < 8; ++ms)
#pragma unroll
      for (int ns = 0; ns < 2; ++ns)
#pragma unroll
        for (int r = 0; r < 4; ++r) {
          float p = __builtin_amdgcn_exp2f(s[ms][ns][r] - mst[ns]);
          s[ms][ns][r] = p;
          tsum[ns] += p;
        }
#pragma unroll
    for (int ns = 0; ns < 2; ++ns) {
      tsum[ns] += __shfl_xor(tsum[ns], 16);
      tsum[ns] += __shfl_xor(tsum[ns], 32);
      lst[ns] = lst[ns] * alpha[ns] + tsum[ns];
    }
#pragma unroll
    for (int ds = 0; ds < 4; ++ds)
#pragma unroll
      for (int ns = 0; ns < 2; ++ns) {
        o[ds][ns][0] *= alpha[ns]; o[ds][ns][1] *= alpha[ns];
        o[ds][ns][2] *= alpha[ns]; o[ds][ns][3] *= alpha[ns];
      }
    __syncthreads();  // ALL waves done reading sK before sP overlays it

    // write P[qrow][key] into per-wave swizzled sP: row=qrow (32), 16 key-chunks
    // chunk c = ms*2 + (qd>>1), half = qd&1; stored chunk pos = c ^ lr
#pragma unroll
    for (int ms = 0; ms < 8; ++ms)
#pragma unroll
      for (int ns = 0; ns < 2; ++ns) {
        uint2 pk;
        pk.x = pk_bf16(s[ms][ns][0], s[ms][ns][1]);
        pk.y = pk_bf16(s[ms][ns][2], s[ms][ns][3]);
        *(uint2*)(sPw + (ns * 16 + lr) * 256 +
                  ((ms * 2 + (qd >> 1)) ^ lr) * 16 + (qd & 1) * 8) = pk;
      }
    asm volatile("s_waitcnt lgkmcnt(0)" ::: "memory");
    // O^T += Vt * P^T
#pragma unroll
    for (int kk = 0; kk < 4; ++kk) {
      bf16x8 pb[2];
#pragma unroll
      for (int ns = 0; ns < 2; ++ns)
        pb[ns] = *(const bf16x8*)(sPw + (ns * 16 + lr) * 256 + (((kk * 4 + qd) ^ lr)) * 16);
#pragma unroll
      for (int ds = 0; ds < 4; ++ds) {
        bf16x8 av = *(const bf16x8*)(sV + (ds * 16 + lr) * 256 +
                                     (((kk * 4 + qd) ^ lr)) * 16);
#pragma unroll
        for (int ns = 0; ns < 2; ++ns)
          o[ds][ns] = __builtin_amdgcn_mfma_f32_16x16x32_bf16(av, pb[ns], o[ds][ns], 0, 0, 0);
      }
    }
  }
  // epilogue: O[qrow][dim] / l -> obuf (B,N,H*d) bf16
#pragma unroll
  for (int ns = 0; ns < 2; ++ns) {
    float rl = 1.0f / lst[ns];
    size_t row = (size_t)(b * 1024 + qrow0 + ns * 16 + lr) * 768 + h * 64;
#pragma unroll
    for (int ds = 0; ds < 4; ++ds) {
      uint2 ov;
      ov.x = pk_bf16(o[ds][ns][0] * rl, o[ds][ns][1] * rl);
      ov.y = pk_bf16(o[ds][ns][2] * rl, o[ds][ns][3] * rl);
      *(uint2*)&ob[row + ds * 16 + qd * 4] = ov;
    }
  }
}

// ---------------- output projection ----------------

__global__ __launch_bounds__(256) void k_proj(const ushort_t* __restrict__ ob,
                                              const ushort_t* __restrict__ WpT,
                                              const float* __restrict__ bproj,
                                              float* __restrict__ out) {
  __shared__ alignas(16) ushort_t sA[128 * 32];
  __shared__ alignas(16) ushort_t sB[128 * 32];
  floatx4 acc[4][4] = {};
  const int m0 = blockIdx.y * 128, n0 = blockIdx.x * 128;
  gemm_bt_mainloop(ob, WpT, m0, n0, sA, sB, acc);
  const int t = threadIdx.x, lane = t & 63, w = t >> 6;
  const int wr = w >> 1, wc = w & 1, lr = lane & 15, qd = lane >> 4;
#pragma unroll
  for (int j = 0; j < 4; ++j) {
    int n = n0 + wc * 64 + j * 16 + lr;
    float bias = bproj[n];
#pragma unroll
    for (int i = 0; i < 4; ++i) {
      int mbase = m0 + wr * 64 + i * 16 + qd * 4;
#pragma unroll
      for (int r = 0; r < 4; ++r)
        out[(size_t)(mbase + r) * 768 + n] = acc[i][j][r] + bias;
    }
  }
}

// ---------------- launch ----------------

extern "C" void kernel_launch(void* const* d_in, const int* in_sizes, int n_in,
                              void* d_out, int out_size, void* d_ws, size_t ws_size,
                              hipStream_t stream) {
  const float* x = (const float*)d_in[0];
  const float* bqkv = (const float*)d_in[2];
  const float* zeta = (const float*)d_in[3];
  const float* bproj = (const float*)d_in[5];
  const unsigned char* mask = (const unsigned char*)d_in[6];
  float* out = (float*)d_out;
  char* ws = (char*)d_ws;
  ushort_t* xb  = (ushort_t*)(ws);              // 16384x768 bf16
  ushort_t* WqT = (ushort_t*)(ws + 25165824);   // 2304x768 bf16
  ushort_t* WpT = (ushort_t*)(ws + 28704768);   // 768x768 bf16
  ushort_t* qb  = (ushort_t*)(ws + 29884416);   // (B,H,N,d) bf16
  ushort_t* kb  = (ushort_t*)(ws + 55050240);   // (B,H,N,d) bf16
  ushort_t* vtb = (ushort_t*)(ws + 80216064);   // (B,H,d,N) bf16
  ushort_t* ob  = xb;  // xb dead after k_qkv; reuse as attention output

  k_cvt_x<<<dim3(6144), dim3(256), 0, stream>>>(x, xb);
  k_transpose_bf16<<<dim3(72, 24), dim3(32, 8), 0, stream>>>((const float*)d_in[1], WqT, 768, 2304);
  k_transpose_bf16<<<dim3(24, 24), dim3(32, 8), 0, stream>>>((const float*)d_in[4], WpT, 768, 768);
  k_qkv<<<dim3(18, 128), dim3(256), 0, stream>>>(xb, WqT, bqkv, zeta, qb, kb, vtb);
  k_attn<<<dim3(1536), dim3(256), 0, stream>>>(qb, kb, vtb, mask, ob);
  k_proj<<<dim3(6, 128), dim3(256), 0, stream>>>(ob, WpT, bproj, out);
}